// Round 6
// baseline (593.316 us; speedup 1.0000x reference)
//
#include <hip/hip_runtime.h>
#include <math.h>

#ifndef M_PI
#define M_PI 3.14159265358979323846
#endif

#define BB     128
#define TT     16384
#define PP     20
#define NCH    18
#define EMIT   256                 // emitted samples per block
#define WARM   128                 // warm-up samples (pole 0.946^128 ~ 8e-4)
#define ROWS   (WARM + EMIT)       // 384 rows in LDS
#define NCHUNK (TT / EMIT)         // 64
#define WEMIT  (EMIT / 4)          // 64 rows emitted per wave
#define VSTR   19                  // padded row stride in float2 (bank-friendly)

typedef float f32x2 __attribute__((ext_vector_type(2)));
typedef float f32x4 __attribute__((ext_vector_type(4)));

// bipolar pair probe indices (LL, LP, RP, RL, Z groups, insertion order)
__constant__ int d_P1[NCH] = {0,4,5,6,  0,1,2,3,  11,15,16,17, 11,12,13,14, 8,9};
__constant__ int d_P2[NCH] = {4,5,6,7,  1,2,3,7,  15,16,17,18, 12,13,14,18, 9,10};

struct Coeffs {
    float b0h, b1h, b2h, a1h, a2h;   // highpass (normalized by a0)
    float b0l, b1l, b2l, a1l, a2l;   // lowpass
};

__global__ __launch_bounds__(256) void collate_iir(
    const float* __restrict__ x, const float* __restrict__ msk,
    float* __restrict__ out, Coeffs cf)
{
    __shared__ f32x2 vpm[ROWS * VSTR];   // 384*19*8 = 58368 B -> 2 blocks/CU

    int blk   = blockIdx.x;
    int chunk = blk & (NCHUNK - 1);
    int b     = blk >> 6;             // blk / NCHUNK
    int t0    = chunk * EMIT;
    int base  = t0 - WARM; if (base < 0) base = 0;
    int nwarm = t0 - base;            // 0 (chunk 0) or 128
    int nrows = nwarm + EMIT;
    int nitems = nrows * NCH;

    const float* xb = x   + ((size_t)b * TT + base) * PP;
    const float* mb = msk + ((size_t)b * TT + base) * PP;

    // ---- conversion: global gather -> (v, pm) float2 in LDS --------------
    // item i = r*18 + c; a wave's 64 items span ~3.5 contiguous rows (~300 B
    // window per array) -> L1 coalesces, HBM streams the slab sequentially.
    for (int i = threadIdx.x; i < nitems; i += 256) {
        int r = i / NCH;              // const-div -> mulhi
        int c = i - r * NCH;
        int p1 = d_P1[c], p2 = d_P2[c];
        int o  = r * PP;
        float m1 = mb[o + p1], m2 = mb[o + p2];
        float x1 = xb[o + p1], x2 = xb[o + p2];
        float pm = m1 * m2;
        f32x2 u;
        u.x = (x1 - x2) * pm;
        u.y = pm;
        vpm[r * VSTR + c] = u;
    }
    __syncthreads();

    // ---- per-wave IIR: wave owns a 64-sample quarter, lanes = channels ----
    int wid  = threadIdx.x >> 6;
    int lane = threadIdx.x & 63;
    if (lane >= NCH) return;
    int c = lane;

    int erow = nwarm + wid * WEMIT;            // first emitted tile-row
    int wrow = erow - WARM; if (wrow < 0) wrow = 0;

    float hx1 = 0.f, hx2 = 0.f, hy1 = 0.f, hy2 = 0.f;   // highpass state
    float lx1 = 0.f, lx2 = 0.f, ly1 = 0.f, ly2 = 0.f;   // lowpass state

    // warm-up from LDS (discard output): 1 ds_read_b64 per step
#pragma unroll 4
    for (int r = wrow; r < erow; ++r) {
        f32x2 u = vpm[r * VSTR + c];
        float v  = u.x;
        float hy = cf.b0h * v + cf.b1h * hx1 + cf.b2h * hx2
                 - cf.a1h * hy1 - cf.a2h * hy2;
        hx2 = hx1; hx1 = v;  hy2 = hy1; hy1 = hy;
        float ly = cf.b0l * hy + cf.b1l * lx1 + cf.b2l * lx2
                 - cf.a1l * ly1 - cf.a2l * ly2;
        lx2 = lx1; lx1 = hy; ly2 = ly1; ly1 = ly;
    }

    // emit region: 64 samples, store as float4 every 4 steps
    size_t rowoff = ((size_t)b * NCH + c) * TT + (size_t)t0 + (size_t)wid * WEMIT;
    float* oe = out + rowoff;                                  // eegs
    float* om = out + (size_t)BB * NCH * TT + rowoff;          // eeg_masks

    for (int gq = 0; gq < WEMIT / 4; ++gq) {
        float be[4], bm[4];
#pragma unroll
        for (int k = 0; k < 4; ++k) {
            f32x2 u = vpm[(erow + gq * 4 + k) * VSTR + c];
            float v  = u.x;
            float hy = cf.b0h * v + cf.b1h * hx1 + cf.b2h * hx2
                     - cf.a1h * hy1 - cf.a2h * hy2;
            hx2 = hx1; hx1 = v;  hy2 = hy1; hy1 = hy;
            float ly = cf.b0l * hy + cf.b1l * lx1 + cf.b2l * lx2
                     - cf.a1l * ly1 - cf.a2l * ly2;
            lx2 = lx1; lx1 = hy; ly2 = ly1; ly1 = ly;
            be[k] = ly;
            bm[k] = u.y;
        }
        f32x4 ve = { be[0], be[1], be[2], be[3] };
        f32x4 vm = { bm[0], bm[1], bm[2], bm[3] };
        *reinterpret_cast<f32x4*>(oe + gq * 4) = ve;
        *reinterpret_cast<f32x4*>(om + gq * 4) = vm;
    }
}

extern "C" void kernel_launch(void* const* d_in, const int* in_sizes, int n_in,
                              void* d_out, int out_size, void* d_ws, size_t ws_size,
                              hipStream_t stream)
{
    const float* x = (const float*)d_in[0];
    const float* m = (const float*)d_in[1];
    float* out = (float*)d_out;

    const double sr = 40.0, q = 0.7071067811865476;
    Coeffs cf;
    {   // highpass fc = 0.5
        double w0 = 2.0 * M_PI * 0.5 / sr;
        double al = sin(w0) / (2.0 * q);
        double cw = cos(w0);
        double a0 = 1.0 + al;
        cf.b0h = (float)(((1.0 + cw) * 0.5) / a0);
        cf.b1h = (float)((-(1.0 + cw)) / a0);
        cf.b2h = cf.b0h;
        cf.a1h = (float)((-2.0 * cw) / a0);
        cf.a2h = (float)((1.0 - al) / a0);
    }
    {   // lowpass fc = 50
        double w0 = 2.0 * M_PI * 50.0 / sr;
        double al = sin(w0) / (2.0 * q);
        double cw = cos(w0);
        double a0 = 1.0 + al;
        cf.b0l = (float)(((1.0 - cw) * 0.5) / a0);
        cf.b1l = (float)((1.0 - cw) / a0);
        cf.b2l = cf.b0l;
        cf.a1l = (float)((-2.0 * cw) / a0);
        cf.a2l = (float)((1.0 - al) / a0);
    }

    int grid  = BB * NCHUNK;   // 8192 blocks, one per (batch, 256-sample chunk)
    collate_iir<<<grid, 256, 0, stream>>>(x, m, out, cf);
}

// Round 7
// 326.850 us; speedup vs baseline: 1.8153x; 1.8153x over previous
//
#include <hip/hip_runtime.h>
#include <math.h>

#ifndef M_PI
#define M_PI 3.14159265358979323846
#endif

#define BB     128
#define TT     16384
#define PP     20
#define NCH    18
#define EMIT   256                 // emitted samples per block
#define WARM   128                 // warm-up samples (pole 0.946^128 ~ 8e-4)
#define ROWS   (WARM + EMIT)       // 384 rows in LDS
#define NCHUNK (TT / EMIT)         // 64
#define WEMIT  (EMIT / 4)          // 64 rows emitted per wave

typedef float f32x2 __attribute__((ext_vector_type(2)));
typedef float f32x4 __attribute__((ext_vector_type(4)));

// bipolar pair probe indices (LL, LP, RP, RL, Z groups, insertion order)
__constant__ int d_P1[NCH] = {0,4,5,6,  0,1,2,3,  11,15,16,17, 11,12,13,14, 8,9};
__constant__ int d_P2[NCH] = {4,5,6,7,  1,2,3,7,  15,16,17,18, 12,13,14,18, 9,10};

struct Coeffs {
    float b0h, b1h, b2h, a1h, a2h;   // highpass (normalized by a0)
    float b0l, b1l, b2l, a1l, a2l;   // lowpass
};

__global__ __launch_bounds__(256) void collate_iir(
    const float* __restrict__ x, const float* __restrict__ msk,
    float* __restrict__ out, Coeffs cf)
{
    // interleaved (x, m) per (row, probe): one ds_read_b64 yields both
    __shared__ f32x2 sxm[ROWS * PP];   // 384*20*8 = 61440 B -> 2 blocks/CU

    int blk   = blockIdx.x;
    int chunk = blk & (NCHUNK - 1);
    int b     = blk >> 6;             // blk / NCHUNK
    int t0    = chunk * EMIT;
    int base  = t0 - WARM; if (base < 0) base = 0;
    int nwarm = t0 - base;            // 0 (chunk 0) or 128
    int nrows = nwarm + EMIT;
    int nel   = nrows * PP;           // 5120 or 7680 scalars per array

    const float* xb = x   + ((size_t)b * TT + base) * PP;
    const float* mb = msk + ((size_t)b * TT + base) * PP;

    // ---- staging: coalesced b32 loads, contiguous b64 LDS writes ---------
    // lane l writes sxm[base+l] -> 512B contiguous per wave, conflict-free.
#pragma unroll 2
    for (int i = threadIdx.x; i < nel; i += 256) {
        f32x2 u;
        u.x = xb[i];
        u.y = mb[i];
        sxm[i] = u;
    }
    __syncthreads();

    // ---- per-wave IIR: wave owns a 64-sample quarter, lanes = channels ----
    int wid  = threadIdx.x >> 6;
    int lane = threadIdx.x & 63;
    if (lane >= NCH) return;
    int c  = lane;
    int p1 = d_P1[c], p2 = d_P2[c];

    int erow = nwarm + wid * WEMIT;            // first emitted tile-row
    int wrow = erow - WARM; if (wrow < 0) wrow = 0;

    float hx1 = 0.f, hx2 = 0.f, hy1 = 0.f, hy2 = 0.f;   // highpass state
    float lx1 = 0.f, lx2 = 0.f, ly1 = 0.f, ly2 = 0.f;   // lowpass state

    // warm-up from LDS (discard output): 2 ds_read_b64 per step
#pragma unroll 4
    for (int r = wrow; r < erow; ++r) {
        int o = r * PP;
        f32x2 u1 = sxm[o + p1];
        f32x2 u2 = sxm[o + p2];
        float pm = u1.y * u2.y;
        float v  = (u1.x - u2.x) * pm;
        float hy = cf.b0h * v + cf.b1h * hx1 + cf.b2h * hx2
                 - cf.a1h * hy1 - cf.a2h * hy2;
        hx2 = hx1; hx1 = v;  hy2 = hy1; hy1 = hy;
        float ly = cf.b0l * hy + cf.b1l * lx1 + cf.b2l * lx2
                 - cf.a1l * ly1 - cf.a2l * ly2;
        lx2 = lx1; lx1 = hy; ly2 = ly1; ly1 = ly;
    }

    // emit region: 64 samples, store as float4 every 4 steps
    size_t rowoff = ((size_t)b * NCH + c) * TT + (size_t)t0 + (size_t)wid * WEMIT;
    float* oe = out + rowoff;                                  // eegs
    float* om = out + (size_t)BB * NCH * TT + rowoff;          // eeg_masks

    for (int gq = 0; gq < WEMIT / 4; ++gq) {
        float be[4], bm[4];
#pragma unroll
        for (int k = 0; k < 4; ++k) {
            int o = (erow + gq * 4 + k) * PP;
            f32x2 u1 = sxm[o + p1];
            f32x2 u2 = sxm[o + p2];
            float pm = u1.y * u2.y;
            float v  = (u1.x - u2.x) * pm;
            float hy = cf.b0h * v + cf.b1h * hx1 + cf.b2h * hx2
                     - cf.a1h * hy1 - cf.a2h * hy2;
            hx2 = hx1; hx1 = v;  hy2 = hy1; hy1 = hy;
            float ly = cf.b0l * hy + cf.b1l * lx1 + cf.b2l * lx2
                     - cf.a1l * ly1 - cf.a2l * ly2;
            lx2 = lx1; lx1 = hy; ly2 = ly1; ly1 = ly;
            be[k] = ly;
            bm[k] = pm;
        }
        f32x4 ve = { be[0], be[1], be[2], be[3] };
        f32x4 vm = { bm[0], bm[1], bm[2], bm[3] };
        *reinterpret_cast<f32x4*>(oe + gq * 4) = ve;
        *reinterpret_cast<f32x4*>(om + gq * 4) = vm;
    }
}

extern "C" void kernel_launch(void* const* d_in, const int* in_sizes, int n_in,
                              void* d_out, int out_size, void* d_ws, size_t ws_size,
                              hipStream_t stream)
{
    const float* x = (const float*)d_in[0];
    const float* m = (const float*)d_in[1];
    float* out = (float*)d_out;

    const double sr = 40.0, q = 0.7071067811865476;
    Coeffs cf;
    {   // highpass fc = 0.5
        double w0 = 2.0 * M_PI * 0.5 / sr;
        double al = sin(w0) / (2.0 * q);
        double cw = cos(w0);
        double a0 = 1.0 + al;
        cf.b0h = (float)(((1.0 + cw) * 0.5) / a0);
        cf.b1h = (float)((-(1.0 + cw)) / a0);
        cf.b2h = cf.b0h;
        cf.a1h = (float)((-2.0 * cw) / a0);
        cf.a2h = (float)((1.0 - al) / a0);
    }
    {   // lowpass fc = 50
        double w0 = 2.0 * M_PI * 50.0 / sr;
        double al = sin(w0) / (2.0 * q);
        double cw = cos(w0);
        double a0 = 1.0 + al;
        cf.b0l = (float)(((1.0 - cw) * 0.5) / a0);
        cf.b1l = (float)((1.0 - cw) / a0);
        cf.b2l = cf.b0l;
        cf.a1l = (float)((-2.0 * cw) / a0);
        cf.a2l = (float)((1.0 - al) / a0);
    }

    int grid  = BB * NCHUNK;   // 8192 blocks, one per (batch, 256-sample chunk)
    collate_iir<<<grid, 256, 0, stream>>>(x, m, out, cf);
}